// Round 1
// baseline (4500.914 us; speedup 1.0000x reference)
//
#include <hip/hip_runtime.h>
#include <stdint.h>

// Spiking neural network:
//   B=32 batches, S=1024 steps, I=256 inputs, H=512 hidden, O=256 outputs.
// Phase 1: ic[B*S, H] (f64) = x[B*S, I] @ Win[I, H]      (feeds spike decisions -> f64)
// Phase 2: sequential scan per batch, f64 membrane state, sparse lateral sums.
//          Emits spike bitmasks [B, S, 8 x u64].
// Phase 3: out[B*S, O] (f32) = spikes @ Wout  via bitmask-driven sparse row sums.
//
// All decision-feeding arithmetic is f64: f32 inputs convert exactly, so our
// membrane potentials match a float64 numpy reference to ~1e-13, which is far
// below any spike-decision margin that lets the harness's own f32-vs-ref
// comparison pass. Output GEMM does not feed back -> f64 accum is free anyway.

#define BB 32
#define SS 1024
#define II 256
#define HH 512
#define OO 256

// ---------------- Phase 1: f64-accumulate tiled GEMM ----------------
// ic[M, H] = x[M, I] @ win[I, H], M = B*S = 32768.
#define TM 64
#define TN 64
#define TK 16

__global__ __launch_bounds__(256) void ic_gemm_f64(const float* __restrict__ x,
                                                   const float* __restrict__ win,
                                                   double* __restrict__ ic) {
    __shared__ float As[TK][TM + 4];  // transposed: As[k][m], padded row = 68 floats (272B, 16B-aligned rows)
    __shared__ float Bs[TK][TN];      // Bs[k][n]
    const int tid = threadIdx.x;
    const int m0 = blockIdx.x * TM;
    const int n0 = blockIdx.y * TN;
    const int tx = tid & 15;   // n-subtile
    const int ty = tid >> 4;   // m-subtile

    double acc[4][4];
#pragma unroll
    for (int i = 0; i < 4; ++i)
#pragma unroll
        for (int j = 0; j < 4; ++j) acc[i][j] = 0.0;

    const int lr = tid >> 2;  // 0..63 : m-row for A load
    const int lq = tid & 3;   // 0..3  : k-quad for A load
    const int br = tid >> 4;  // 0..15 : k-row for B load
    const int bq = tid & 15;  // 0..15 : n-quad for B load

    for (int k0 = 0; k0 < II; k0 += TK) {
        float4 av = *(const float4*)(x + (size_t)(m0 + lr) * II + k0 + lq * 4);
        float4 bv = *(const float4*)(win + (size_t)(k0 + br) * HH + n0 + bq * 4);
        As[lq * 4 + 0][lr] = av.x;
        As[lq * 4 + 1][lr] = av.y;
        As[lq * 4 + 2][lr] = av.z;
        As[lq * 4 + 3][lr] = av.w;
        *(float4*)(&Bs[br][bq * 4]) = bv;
        __syncthreads();
#pragma unroll
        for (int kk = 0; kk < TK; ++kk) {
            float4 a = *(const float4*)(&As[kk][ty * 4]);
            float4 b = *(const float4*)(&Bs[kk][tx * 4]);
            const double a0 = (double)a.x, a1 = (double)a.y, a2 = (double)a.z, a3 = (double)a.w;
            const double b0 = (double)b.x, b1 = (double)b.y, b2 = (double)b.z, b3 = (double)b.w;
            acc[0][0] += a0 * b0; acc[0][1] += a0 * b1; acc[0][2] += a0 * b2; acc[0][3] += a0 * b3;
            acc[1][0] += a1 * b0; acc[1][1] += a1 * b1; acc[1][2] += a1 * b2; acc[1][3] += a1 * b3;
            acc[2][0] += a2 * b0; acc[2][1] += a2 * b1; acc[2][2] += a2 * b2; acc[2][3] += a2 * b3;
            acc[3][0] += a3 * b0; acc[3][1] += a3 * b1; acc[3][2] += a3 * b2; acc[3][3] += a3 * b3;
        }
        __syncthreads();
    }

#pragma unroll
    for (int i = 0; i < 4; ++i) {
        double* row = ic + (size_t)(m0 + ty * 4 + i) * HH + n0 + tx * 4;
#pragma unroll
        for (int j = 0; j < 4; ++j) row[j] = acc[i][j];
    }
}

// ---------------- Phase 2: sequential scan ----------------
// One block per batch. 1024 threads: threads [0,512) own neuron state and sum
// the first half of the active list; threads [512,1024) sum the second half.
__global__ __launch_bounds__(1024) void snn_scan(const double* __restrict__ ic,
                                                 const float* __restrict__ wlat,
                                                 const float* __restrict__ thr,
                                                 uint64_t* __restrict__ masks) {
    __shared__ unsigned short s_act[HH];  // active-neuron indices for current step
    __shared__ double s_latB[HH];         // partial lateral sums from thread group B
    __shared__ uint64_t s_masks[8];       // per-wave spike masks (waves 0..7)
    __shared__ int s_nact;

    const int tid = threadIdx.x;
    const int b = blockIdx.x;
    const double* icb = ic + (size_t)b * SS * HH;
    uint64_t* mb = masks + (size_t)b * SS * 8;

    double mp = 0.0;       // membrane potential (valid for tid < H)
    int refrac = 0;        // refractory counter in {0,1,2}
    double th = 0.0;
    if (tid < HH) th = (double)thr[tid];
    if (tid == 0) s_nact = 0;
    const int hp = (tid < HH) ? tid : (tid - HH);
    __syncthreads();

    for (int t = 0; t < SS; ++t) {
        // ---- lateral partial sums over active list from previous step ----
        const int n = s_nact;
        const int half = n >> 1;
        const int i0 = (tid < HH) ? 0 : half;
        const int i1 = (tid < HH) ? half : n;
        double acc = 0.0;
#pragma unroll 4
        for (int i = i0; i < i1; ++i) {
            acc += (double)wlat[(size_t)s_act[i] * HH + hp];
        }
        if (tid >= HH) s_latB[hp] = acc;
        __syncthreads();

        // ---- membrane update + spike decision (threads 0..511) ----
        bool spike = false;
        if (tid < HH) {
            const double lat = acc + s_latB[tid];
            mp = 0.95 * mp + icb[(size_t)t * HH + tid] - lat;
            if (refrac > 0) mp = 0.0;
            refrac = (refrac > 0) ? (refrac - 1) : 0;
            spike = (mp >= th);
            if (spike) { mp = 0.0; refrac = 2; }
            const uint64_t bm = __ballot(spike);
            if ((tid & 63) == 0) {
                s_masks[tid >> 6] = bm;
                mb[(size_t)t * 8 + (tid >> 6)] = bm;  // persist for phase 3
            }
        }
        __syncthreads();

        // ---- compact spikes into active list for next step ----
        if (tid < HH) {
            if (spike) {
                const int w = tid >> 6;
                int base = 0;
#pragma unroll
                for (int j = 0; j < 8; ++j)
                    if (j < w) base += __popcll(s_masks[j]);
                base += __popcll(s_masks[w] & ((1ull << (tid & 63)) - 1ull));
                s_act[base] = (unsigned short)tid;
            }
            if (tid == 0) {
                int tot = 0;
#pragma unroll
                for (int j = 0; j < 8; ++j) tot += __popcll(s_masks[j]);
                s_nact = tot;
            }
        }
        __syncthreads();
    }
}

// ---------------- Phase 3: sparse output GEMM from bitmasks ----------------
// out[bt, o] = sum over set bits h of wout[h, o]. One block per (b,t) row.
__global__ __launch_bounds__(256) void out_gemm(const uint64_t* __restrict__ masks,
                                                const float* __restrict__ wout,
                                                float* __restrict__ out) {
    const int bt = blockIdx.x;
    const int o = threadIdx.x;
    __shared__ uint64_t sm[8];
    if (o < 8) sm[o] = masks[(size_t)bt * 8 + o];
    __syncthreads();

    double acc = 0.0;
#pragma unroll
    for (int w = 0; w < 8; ++w) {
        uint64_t bits = sm[w];
        while (bits) {
            const int h = (w << 6) + __ffsll((unsigned long long)bits) - 1;
            bits &= bits - 1;
            acc += (double)wout[(size_t)h * OO + o];
        }
    }
    out[(size_t)bt * OO + o] = (float)acc;
}

extern "C" void kernel_launch(void* const* d_in, const int* in_sizes, int n_in,
                              void* d_out, int out_size, void* d_ws, size_t ws_size,
                              hipStream_t stream) {
    const float* x    = (const float*)d_in[0];  // [B, S, I]
    const float* win  = (const float*)d_in[1];  // [I, H]
    const float* wlat = (const float*)d_in[2];  // [H, H]
    const float* wout = (const float*)d_in[3];  // [H, O]
    const float* thr  = (const float*)d_in[4];  // [H]
    float* out = (float*)d_out;                 // [B, S, O]

    // Workspace layout: ic f64 (128 MB) | spike masks (2 MB). Needs ~130 MB.
    double* ic = (double*)d_ws;
    uint64_t* masks = (uint64_t*)((char*)d_ws + (size_t)BB * SS * HH * sizeof(double));

    const int M = BB * SS;  // 32768
    ic_gemm_f64<<<dim3(M / TM, HH / TN), 256, 0, stream>>>(x, win, ic);
    snn_scan<<<BB, 1024, 0, stream>>>(ic, wlat, thr, masks);
    out_gemm<<<M, 256, 0, stream>>>(masks, wout, out);
}

// Round 2
// 3155.836 us; speedup vs baseline: 1.4262x; 1.4262x over previous
//
#include <hip/hip_runtime.h>
#include <stdint.h>

// Spiking neural network:
//   B=32 batches, S=1024 steps, I=256 inputs, H=512 hidden, O=256 outputs.
// Phase 1: ic[B*S, H] (f64) = x[B*S, I] @ Win[I, H]      (feeds spike decisions -> f64)
// Phase 2: sequential scan per batch, f64 membrane state, sparse lateral sums.
//          Emits spike bitmasks [B, S, 8 x u64].
// Phase 3: out[B*S, O] (f32) = spikes @ Wout  via bitmask-driven sparse row sums.

#define BB 32
#define SS 1024
#define II 256
#define HH 512
#define OO 256

// ---------------- Phase 1: f64-accumulate tiled GEMM ----------------
#define TM 64
#define TN 64
#define TK 16

__global__ __launch_bounds__(256) void ic_gemm_f64(const float* __restrict__ x,
                                                   const float* __restrict__ win,
                                                   double* __restrict__ ic) {
    __shared__ float As[TK][TM + 4];
    __shared__ float Bs[TK][TN];
    const int tid = threadIdx.x;
    const int m0 = blockIdx.x * TM;
    const int n0 = blockIdx.y * TN;
    const int tx = tid & 15;
    const int ty = tid >> 4;

    double acc[4][4];
#pragma unroll
    for (int i = 0; i < 4; ++i)
#pragma unroll
        for (int j = 0; j < 4; ++j) acc[i][j] = 0.0;

    const int lr = tid >> 2;
    const int lq = tid & 3;
    const int br = tid >> 4;
    const int bq = tid & 15;

    for (int k0 = 0; k0 < II; k0 += TK) {
        float4 av = *(const float4*)(x + (size_t)(m0 + lr) * II + k0 + lq * 4);
        float4 bv = *(const float4*)(win + (size_t)(k0 + br) * HH + n0 + bq * 4);
        As[lq * 4 + 0][lr] = av.x;
        As[lq * 4 + 1][lr] = av.y;
        As[lq * 4 + 2][lr] = av.z;
        As[lq * 4 + 3][lr] = av.w;
        *(float4*)(&Bs[br][bq * 4]) = bv;
        __syncthreads();
#pragma unroll
        for (int kk = 0; kk < TK; ++kk) {
            float4 a = *(const float4*)(&As[kk][ty * 4]);
            float4 b = *(const float4*)(&Bs[kk][tx * 4]);
            const double a0 = (double)a.x, a1 = (double)a.y, a2 = (double)a.z, a3 = (double)a.w;
            const double b0 = (double)b.x, b1 = (double)b.y, b2 = (double)b.z, b3 = (double)b.w;
            acc[0][0] += a0 * b0; acc[0][1] += a0 * b1; acc[0][2] += a0 * b2; acc[0][3] += a0 * b3;
            acc[1][0] += a1 * b0; acc[1][1] += a1 * b1; acc[1][2] += a1 * b2; acc[1][3] += a1 * b3;
            acc[2][0] += a2 * b0; acc[2][1] += a2 * b1; acc[2][2] += a2 * b2; acc[2][3] += a2 * b3;
            acc[3][0] += a3 * b0; acc[3][1] += a3 * b1; acc[3][2] += a3 * b2; acc[3][3] += a3 * b3;
        }
        __syncthreads();
    }

#pragma unroll
    for (int i = 0; i < 4; ++i) {
        double* row = ic + (size_t)(m0 + ty * 4 + i) * HH + n0 + tx * 4;
#pragma unroll
        for (int j = 0; j < 4; ++j) row[j] = acc[i][j];
    }
}

// ---------------- Phase 2: sequential scan ----------------
// One block per batch, 1024 threads (group A = neuron owners [0,512),
// group B = [512,1024) sums the second half of the active list).
// 2 barriers/step; next-step active list built via per-wave LDS atomicAdd
// (order nondeterminism only perturbs the f64 sum at ~1e-15).
__global__ __launch_bounds__(1024) void snn_scan(const double* __restrict__ ic,
                                                 const float* __restrict__ wlat,
                                                 const float* __restrict__ thr,
                                                 uint64_t* __restrict__ masks) {
    __shared__ int s_act[2][HH];   // double-buffered active-neuron indices
    __shared__ int s_nact[2];
    __shared__ double s_latB[HH];  // group-B partial lateral sums

    const int tid = threadIdx.x;
    const int b = blockIdx.x;
    const double* icb = ic + (size_t)b * SS * HH;
    uint64_t* mb = masks + (size_t)b * SS * 8;

    double mp = 0.0;
    int refrac = 0;
    double th = 0.0;
    if (tid < HH) th = (double)thr[tid];
    if (tid == 0) { s_nact[0] = 0; s_nact[1] = 0; }
    const int hp = (tid < HH) ? tid : (tid - HH);
    __syncthreads();

    int cur = 0;
    for (int t = 0; t < SS; ++t) {
        const int nxt = cur ^ 1;

        // ---- phase 1: prefetch ic, lateral partial sums, reset next count ----
        double icv = 0.0;
        if (tid < HH) icv = icb[(size_t)t * HH + tid];  // hidden under lateral loop
        if (tid == HH) s_nact[nxt] = 0;                 // group-B wave leader

        const int n = s_nact[cur];
        const int half = n >> 1;
        const int i0 = (tid < HH) ? 0 : half;
        const int i1 = (tid < HH) ? half : n;
        const int* act = s_act[cur];

        double a0 = 0.0, a1 = 0.0, a2 = 0.0, a3 = 0.0,
               a4 = 0.0, a5 = 0.0, a6 = 0.0, a7 = 0.0;
        int i = i0;
        for (; i + 8 <= i1; i += 8) {
            const int h0 = act[i + 0], h1 = act[i + 1], h2 = act[i + 2], h3 = act[i + 3];
            const int h4 = act[i + 4], h5 = act[i + 5], h6 = act[i + 6], h7 = act[i + 7];
            a0 += (double)wlat[(size_t)h0 * HH + hp];
            a1 += (double)wlat[(size_t)h1 * HH + hp];
            a2 += (double)wlat[(size_t)h2 * HH + hp];
            a3 += (double)wlat[(size_t)h3 * HH + hp];
            a4 += (double)wlat[(size_t)h4 * HH + hp];
            a5 += (double)wlat[(size_t)h5 * HH + hp];
            a6 += (double)wlat[(size_t)h6 * HH + hp];
            a7 += (double)wlat[(size_t)h7 * HH + hp];
        }
        for (; i < i1; ++i) a0 += (double)wlat[(size_t)act[i] * HH + hp];
        const double lacc = ((a0 + a1) + (a2 + a3)) + ((a4 + a5) + (a6 + a7));
        if (tid >= HH) s_latB[hp] = lacc;
        __syncthreads();

        // ---- phase 2 (group A): membrane update + spike + build next list ----
        if (tid < HH) {
            const double lat = lacc + s_latB[tid];
            mp = 0.95 * mp + icv - lat;
            if (refrac > 0) mp = 0.0;
            refrac = (refrac > 0) ? (refrac - 1) : 0;
            const bool spike = (mp >= th);
            if (spike) { mp = 0.0; refrac = 2; }

            const uint64_t bm = __ballot(spike);
            const int lane = tid & 63;
            const int cnt = __popcll(bm);
            int base = 0;
            if (lane == 0) {
                mb[(size_t)t * 8 + (tid >> 6)] = bm;  // persist for phase 3
                if (cnt) base = atomicAdd(&s_nact[nxt], cnt);
            }
            base = __shfl(base, 0);
            if (spike) {
                s_act[nxt][base + __popcll(bm & ((1ull << lane) - 1ull))] = tid;
            }
        }
        __syncthreads();
        cur = nxt;
    }
}

// ---------------- Phase 3: sparse output GEMM from bitmasks ----------------
__global__ __launch_bounds__(256) void out_gemm(const uint64_t* __restrict__ masks,
                                                const float* __restrict__ wout,
                                                float* __restrict__ out) {
    const int bt = blockIdx.x;
    const int o = threadIdx.x;
    __shared__ uint64_t sm[8];
    if (o < 8) sm[o] = masks[(size_t)bt * 8 + o];
    __syncthreads();

    float acc = 0.0f;
#pragma unroll
    for (int w = 0; w < 8; ++w) {
        uint64_t bits = sm[w];
        while (bits) {
            const int h = (w << 6) + __ffsll((unsigned long long)bits) - 1;
            bits &= bits - 1;
            acc += wout[(size_t)h * OO + o];
        }
    }
    out[(size_t)bt * OO + o] = acc;
}

extern "C" void kernel_launch(void* const* d_in, const int* in_sizes, int n_in,
                              void* d_out, int out_size, void* d_ws, size_t ws_size,
                              hipStream_t stream) {
    const float* x    = (const float*)d_in[0];  // [B, S, I]
    const float* win  = (const float*)d_in[1];  // [I, H]
    const float* wlat = (const float*)d_in[2];  // [H, H]
    const float* wout = (const float*)d_in[3];  // [H, O]
    const float* thr  = (const float*)d_in[4];  // [H]
    float* out = (float*)d_out;                 // [B, S, O]

    double* ic = (double*)d_ws;
    uint64_t* masks = (uint64_t*)((char*)d_ws + (size_t)BB * SS * HH * sizeof(double));

    const int M = BB * SS;  // 32768
    ic_gemm_f64<<<dim3(M / TM, HH / TN), 256, 0, stream>>>(x, win, ic);
    snn_scan<<<BB, 1024, 0, stream>>>(ic, wlat, thr, masks);
    out_gemm<<<M, 256, 0, stream>>>(masks, wout, out);
}